// Round 5
// baseline (22329.407 us; speedup 1.0000x reference)
//
#include <hip/hip_runtime.h>
#include <math.h>
#include <limits.h>

#define T_STEPS 16384
#define IN_DIM  14
#define H_DIM   100
#define G_DIM   300   // 3*H

// LDS float offsets inside each 1024-float double buffer.
#define H1OFF 0      // block0: h1[0..100)
#define H2OFF 132    // block2: h2[0..100)  (132*4=528, 16B aligned)
#define AOFF  256    // block1: a slab [0..300)

typedef float f2 __attribute__((ext_vector_type(2)));
typedef float f4 __attribute__((ext_vector_type(4)));

#define REP25(M) M(0) M(1) M(2) M(3) M(4) M(5) M(6) M(7) M(8) M(9) M(10) M(11) \
                 M(12) M(13) M(14) M(15) M(16) M(17) M(18) M(19) M(20) M(21) M(22) M(23) M(24)

// ---------------- Phase 0: gi0[t][j] = b_ih0[j] + sum_k x[t][k]*w_ih0[j][k] ----------------
__global__ void gi0_kernel(const float* __restrict__ x,
                           const float* __restrict__ w_ih0,
                           const float* __restrict__ b_ih0,
                           float* __restrict__ gi0) {
    int e = blockIdx.x * blockDim.x + threadIdx.x;
    if (e >= T_STEPS * G_DIM) return;
    int t = e / G_DIM;
    int j = e - t * G_DIM;
    const float* xr = x + t * IN_DIM;
    const float* wr = w_ih0 + j * IN_DIM;
    float acc = b_ih0[j];
    #pragma unroll
    for (int k = 0; k < IN_DIM; ++k) acc = fmaf(xr[k], wr[k], acc);
    gi0[e] = acc;
}

// ---------------- Phase 1: THREE persistent workgroups ----------------
// ROUND 5 root cause (VGPR_Count 120/224/64/84 across rounds vs plans of
// 200/400/100/100 weight floats): the allocator ALWAYS demoted weight values
// to AGPRs; v_pk_fma_f32 can't consume them in place, costing ~1.7 copy-VALU
// per weight float per iter (R2 accounting: 1010 instr/wave/iter vs ~320
// algorithmic). Fix: run the FMA through inline asm with "v" constraints --
// a vreg with a VGPR-class-constrained use is VGPR-class for its whole live
// range. Requires pressure <= 256 arch VGPRs: 100 weight floats + ~70
// working at 2 waves/SIMD. 90K weight floats -> ~900 lanes -> 3 blocks:
//   block0: layer-0 recurrence. waves 0-4 gate layout over w_hh0 (20 gates/
//     wave; lanes 0-19 r, 20-39 z, 40-59 n, 60-63 clone; 1 row = 100 fl/lane;
//     bpermute combine). wave5 gi0->LDS ring. wave6 h1 publisher -> global.
//   block1: a(t) = b_ih1 + w_ih1 . h1(t) (non-recurrent). waves 0-4: 60
//     rows/wave, 1 row/lane. wave5 h1 prefetcher (global->LDS ring, flag-
//     gated). wave6 a publisher -> global.
//   block2: layer-1 recurrence. waves 0-4 gate layout over w_hh1 (reads a
//     from LDS ring, h2 in LDS dbuf). wave5 a prefetcher. + FC epilogue.
// Deps flow block0 -> block1 -> block2 only (full-history buffers: producers
// never wait -> completes even if blocks serialize; ring+backpressure
// fallback for small ws needs co-residency, as R4 shipped). Agent-scope
// atomics for cross-XCD safety. All accumulation chains, reduce order and
// gate formulas verbatim from R3/R4 -> bit-identical (absmax 0.0).
__global__ __launch_bounds__(448, 2)
void gru3_kernel(const float* __restrict__ gi0,
                 const float* __restrict__ w_hh0, const float* __restrict__ b_hh0,
                 const float* __restrict__ w_ih1, const float* __restrict__ b_ih1,
                 const float* __restrict__ w_hh1, const float* __restrict__ b_hh1,
                 const float* __restrict__ fc_w,  const float* __restrict__ fc_b,
                 float* __restrict__ out,
                 float* __restrict__ h1g, float* __restrict__ ag, int* flags,
                 int rm1, int rmA, int bp1, int bpA) {
    __shared__ __align__(16) float bufA[1024];
    __shared__ __align__(16) float bufB[1024];
    __shared__ __align__(16) float giring[4 * 304];  // block0: gi0 rows
    __shared__ __align__(16) float h1ring[4 * 128];  // block1: h1 steps
    __shared__ __align__(16) float aring [4 * 304];  // block2: a steps

    const int tid  = threadIdx.x;
    const int wave = tid >> 6;
    const int ln   = tid & 63;
    int* h1prod = flags;        // h1 steps published /8   (block0 -> block1)
    int* h1cons = flags + 32;   // h1 steps consumed /8    (block1 -> block0 bp)
    int* aprod  = flags + 64;   // a steps published /8    (block1 -> block2)
    int* acons  = flags + 96;   // a steps consumed /8     (block2 -> block1 bp)

    for (int kk = tid; kk < 1024; kk += 448) { bufA[kk] = 0.0f; bufB[kk] = 0.0f; }
    __syncthreads();

    // gate-wave layout constants (meaningful for waves 0-4 of blocks 0/2)
    const int ln20  = ln % 20;
    const int role  = ln / 20;                 // 0=r, 1=z, 2=n, 3=clone
    const int roleC = (role > 2) ? 2 : role;
    const bool isR  = (role == 0);
    const int q     = wave * 20 + ln20;        // gate id 0..99
    const int adZ   = (20 + ln20) << 2;        // bpermute addr of z partner
    const int adN   = (40 + ln20) << 2;        // bpermute addr of n partner

    // ---- weight row: 50 named f2 (100 f32). VGPR class forced by asm use. ----
    #define DECLK(k) f2 wa_##k, wb_##k;
    REP25(DECLK)
    #undef DECLK
    float bias = 0.0f;
    #define LOADK(k) { f4 V = p_[k]; wa_##k = V.lo; wb_##k = V.hi; }
    // DOTK: packed-f32 FMA via inline asm ("v" constraints pin weights AND
    // accs to arch VGPRs -- the entire point of this round). Same math and
    // order as the previous C++ `acc += w * v` chains.
    #define DOTK(k) { f4 V_ = hb4_[k]; \
        asm("v_pk_fma_f32 %0, %2, %4, %0\n\t" \
            "v_pk_fma_f32 %1, %3, %5, %1" \
            : "+v"(accA), "+v"(accB) \
            : "v"(wa_##k), "v"(wb_##k), "v"(V_.lo), "v"(V_.hi)); }

    if (blockIdx.x == 0) {
        // =============== block0: layer-0 recurrence ===============
        if (wave < 5) {
            const int row = roleC * 100 + q;
            bias = b_hh0[row];
            const f4* p_ = reinterpret_cast<const f4*>(w_hh0 + (size_t)row * H_DIM);
            REP25(LOADK)
        }
        if (wave == 5) {   // prologue: gi0 rows 0,1 -> ring
            #pragma unroll
            for (int r = 0; r < 2; ++r) {
                const f4* src = reinterpret_cast<const f4*>(gi0 + (size_t)r * G_DIM);
                f4* dst = reinterpret_cast<f4*>(giring + r * 304);
                dst[ln] = src[ln];
                if (ln < 11) dst[64 + ln] = src[64 + ln];
            }
        }
        __syncthreads();

        int cons_c = 0;
        for (int t = 0; t <= T_STEPS; ++t) {
            float* bc = (t & 1) ? bufB : bufA;
            float* bn = (t & 1) ? bufA : bufB;
            if (wave < 5) {
                float g_r = 0.f, g_z = 0.f, g_n = 0.f, hold = 0.f;
                if (isR) {
                    if (t < T_STEPS) {
                        const float* gi = giring + (t & 3) * 304;
                        g_r = gi[q]; g_z = gi[100 + q]; g_n = gi[200 + q];
                    }
                    hold = bc[H1OFF + q];
                }
                const f4* hb4_ = reinterpret_cast<const f4*>(bc + H1OFF);
                f2 accA, accB;
                accA.x = bias; accA.y = 0.0f; accB.x = 0.0f; accB.y = 0.0f;
                REP25(DOTK)
                float d = (accA.x + accB.x) + (accA.y + accB.y);
                float dz = __int_as_float(__builtin_amdgcn_ds_bpermute(adZ, __float_as_int(d)));
                float dn = __int_as_float(__builtin_amdgcn_ds_bpermute(adN, __float_as_int(d)));
                if (isR && t < T_STEPS) {
                    float r = 1.0f / (1.0f + expf(-(g_r + d)));
                    float z = 1.0f / (1.0f + expf(-(g_z + dz)));
                    float n = tanhf(g_n + r * dn);
                    bn[H1OFF + q] = (1.0f - z) * n + z * hold;
                }
            } else if (wave == 5) {
                const int r = t + 2;
                if (r <= T_STEPS - 1) {
                    const f4* src = reinterpret_cast<const f4*>(gi0 + (size_t)r * G_DIM);
                    f4* dst = reinterpret_cast<f4*>(giring + (r & 3) * 304);
                    f4 v0 = src[ln];
                    dst[ln] = v0;
                    if (ln < 11) { f4 v1 = src[64 + ln]; dst[64 + ln] = v1; }
                }
            } else if (wave == 6) {
                if (t >= 1) {   // publish h1(t-1)
                    const int e = t - 1;
                    while (e - cons_c >= bp1)
                        cons_c = 8 * __hip_atomic_load(h1cons, __ATOMIC_ACQUIRE, __HIP_MEMORY_SCOPE_AGENT);
                    float* dstb = h1g + (size_t)(e & rm1) * H_DIM;
                    float v0 = bc[H1OFF + ln];
                    __hip_atomic_store(dstb + ln, v0, __ATOMIC_RELAXED, __HIP_MEMORY_SCOPE_AGENT);
                    if (ln < 36) {
                        float v1 = bc[H1OFF + 64 + ln];
                        __hip_atomic_store(dstb + 64 + ln, v1, __ATOMIC_RELAXED, __HIP_MEMORY_SCOPE_AGENT);
                    }
                    if ((t & 7) == 0) {
                        __threadfence();
                        if (ln == 0)
                            __hip_atomic_store(h1prod, t >> 3, __ATOMIC_RELEASE, __HIP_MEMORY_SCOPE_AGENT);
                    }
                }
            }
            __syncthreads();
        }
    } else if (blockIdx.x == 1) {
        // =============== block1: a(t) = b_ih1 + w_ih1 . h1(t) ===============
        const int rl = (ln < 60) ? ln : 59;          // lanes 60-63 clone
        const int row = wave * 60 + rl;              // valid for wave<5
        if (wave < 5) {
            bias = b_ih1[row];
            const f4* p_ = reinterpret_cast<const f4*>(w_ih1 + (size_t)row * H_DIM);
            REP25(LOADK)
        }
        int prod_c = 0;
        if (wave == 5) {   // prologue: h1(0) -> ring slot 0 (flag-gated)
            while (prod_c <= 0)
                prod_c = 8 * __hip_atomic_load(h1prod, __ATOMIC_ACQUIRE, __HIP_MEMORY_SCOPE_AGENT);
            h1ring[ln] = __hip_atomic_load(h1g + ln, __ATOMIC_RELAXED, __HIP_MEMORY_SCOPE_AGENT);
            if (ln < 36)
                h1ring[64 + ln] = __hip_atomic_load(h1g + 64 + ln, __ATOMIC_RELAXED, __HIP_MEMORY_SCOPE_AGENT);
        }
        __syncthreads();

        int cons_c = 0;
        for (int u = 0; u <= T_STEPS; ++u) {
            float* bc = (u & 1) ? bufB : bufA;
            float* bn = (u & 1) ? bufA : bufB;
            if (wave < 5) {
                if (u < T_STEPS) {
                    const f4* hb4_ = reinterpret_cast<const f4*>(h1ring + (u & 3) * 128);
                    f2 accA, accB;
                    accA.x = bias; accA.y = 0.0f; accB.x = 0.0f; accB.y = 0.0f;
                    REP25(DOTK)
                    float d = (accA.x + accB.x) + (accA.y + accB.y);
                    if (ln < 60) bn[AOFF + row] = d;
                }
            } else if (wave == 5) {
                const int e = u + 1;   // prefetch h1(u+1)
                if (e <= T_STEPS - 1) {
                    while (prod_c <= e)
                        prod_c = 8 * __hip_atomic_load(h1prod, __ATOMIC_ACQUIRE, __HIP_MEMORY_SCOPE_AGENT);
                    const float* srcb = h1g + (size_t)(e & rm1) * H_DIM;
                    float* dst = h1ring + (e & 3) * 128;
                    dst[ln] = __hip_atomic_load(srcb + ln, __ATOMIC_RELAXED, __HIP_MEMORY_SCOPE_AGENT);
                    if (ln < 36)
                        dst[64 + ln] = __hip_atomic_load(srcb + 64 + ln, __ATOMIC_RELAXED, __HIP_MEMORY_SCOPE_AGENT);
                }
                if ((u & 7) == 7 && ln == 0)
                    __hip_atomic_store(h1cons, (u + 1) >> 3, __ATOMIC_RELAXED, __HIP_MEMORY_SCOPE_AGENT);
            } else if (wave == 6) {
                if (u >= 1) {   // publish a(u-1) (in bc[AOFF..))
                    const int e = u - 1;
                    while (e - cons_c >= bpA)
                        cons_c = 8 * __hip_atomic_load(acons, __ATOMIC_ACQUIRE, __HIP_MEMORY_SCOPE_AGENT);
                    float* dstb = ag + (size_t)(e & rmA) * G_DIM;
                    __hip_atomic_store(dstb + ln,       bc[AOFF + ln],       __ATOMIC_RELAXED, __HIP_MEMORY_SCOPE_AGENT);
                    __hip_atomic_store(dstb + 64 + ln,  bc[AOFF + 64 + ln],  __ATOMIC_RELAXED, __HIP_MEMORY_SCOPE_AGENT);
                    __hip_atomic_store(dstb + 128 + ln, bc[AOFF + 128 + ln], __ATOMIC_RELAXED, __HIP_MEMORY_SCOPE_AGENT);
                    __hip_atomic_store(dstb + 192 + ln, bc[AOFF + 192 + ln], __ATOMIC_RELAXED, __HIP_MEMORY_SCOPE_AGENT);
                    if (ln < 44)
                        __hip_atomic_store(dstb + 256 + ln, bc[AOFF + 256 + ln], __ATOMIC_RELAXED, __HIP_MEMORY_SCOPE_AGENT);
                    if ((u & 7) == 0) {
                        __threadfence();
                        if (ln == 0)
                            __hip_atomic_store(aprod, u >> 3, __ATOMIC_RELEASE, __HIP_MEMORY_SCOPE_AGENT);
                    }
                }
            }
            __syncthreads();
        }
    } else {
        // =============== block2: layer-1 recurrence + FC ===============
        if (wave < 5) {
            const int row = roleC * 100 + q;
            bias = b_hh1[row];
            const f4* p_ = reinterpret_cast<const f4*>(w_hh1 + (size_t)row * H_DIM);
            REP25(LOADK)
        }
        int prod_c = 0;
        for (int k2 = 0; k2 <= T_STEPS + 1; ++k2) {
            float* bc = (k2 & 1) ? bufB : bufA;
            float* bn = (k2 & 1) ? bufA : bufB;
            if (wave < 5) {
                float g_r = 0.f, g_z = 0.f, g_n = 0.f, hold = 0.f;
                if (isR) {
                    if (k2 >= 2) {
                        const float* ap = aring + ((k2 - 2) & 3) * 304;
                        g_r = ap[q]; g_z = ap[100 + q]; g_n = ap[200 + q];
                    }
                    hold = bc[H2OFF + q];
                }
                const f4* hb4_ = reinterpret_cast<const f4*>(bc + H2OFF);
                f2 accA, accB;
                accA.x = bias; accA.y = 0.0f; accB.x = 0.0f; accB.y = 0.0f;
                REP25(DOTK)
                float d = (accA.x + accB.x) + (accA.y + accB.y);
                float dz = __int_as_float(__builtin_amdgcn_ds_bpermute(adZ, __float_as_int(d)));
                float dn = __int_as_float(__builtin_amdgcn_ds_bpermute(adN, __float_as_int(d)));
                if (isR && k2 >= 2) {   // h2(k2-2)
                    float r = 1.0f / (1.0f + expf(-(g_r + d)));
                    float z = 1.0f / (1.0f + expf(-(g_z + dz)));
                    float n = tanhf(g_n + r * dn);
                    bn[H2OFF + q] = (1.0f - z) * n + z * hold;
                }
            } else if (wave == 5) {
                const int e = k2;   // prefetch a(k2), consumed at iter k2+2
                if (e <= T_STEPS - 1) {
                    while (prod_c <= e)
                        prod_c = 8 * __hip_atomic_load(aprod, __ATOMIC_ACQUIRE, __HIP_MEMORY_SCOPE_AGENT);
                    const float* srcb = ag + (size_t)(e & rmA) * G_DIM;
                    float* dst = aring + (e & 3) * 304;
                    dst[ln]       = __hip_atomic_load(srcb + ln,       __ATOMIC_RELAXED, __HIP_MEMORY_SCOPE_AGENT);
                    dst[64 + ln]  = __hip_atomic_load(srcb + 64 + ln,  __ATOMIC_RELAXED, __HIP_MEMORY_SCOPE_AGENT);
                    dst[128 + ln] = __hip_atomic_load(srcb + 128 + ln, __ATOMIC_RELAXED, __HIP_MEMORY_SCOPE_AGENT);
                    dst[192 + ln] = __hip_atomic_load(srcb + 192 + ln, __ATOMIC_RELAXED, __HIP_MEMORY_SCOPE_AGENT);
                    if (ln < 44)
                        dst[256 + ln] = __hip_atomic_load(srcb + 256 + ln, __ATOMIC_RELAXED, __HIP_MEMORY_SCOPE_AGENT);
                }
                if ((k2 & 7) == 7 && ln == 0)
                    __hip_atomic_store(acons, (k2 + 1) >> 3, __ATOMIC_RELAXED, __HIP_MEMORY_SCOPE_AGENT);
            }
            __syncthreads();
        }
        // FC epilogue: h2(T-1) written at k2=T+1 (odd) -> bufA.
        if (tid < 64) {
            float s = 0.0f;
            for (int j = tid; j < H_DIM; j += 64) s = fmaf(fc_w[j], bufA[H2OFF + j], s);
            #pragma unroll
            for (int off = 32; off > 0; off >>= 1) s += __shfl_down(s, off);
            if (tid == 0) out[0] = s + fc_b[0];
        }
    }
    #undef DOTK
    #undef LOADK
}

extern "C" void kernel_launch(void* const* d_in, const int* in_sizes, int n_in,
                              void* d_out, int out_size, void* d_ws, size_t ws_size,
                              hipStream_t stream) {
    const float* x     = (const float*)d_in[0];
    const float* w_ih0 = (const float*)d_in[1];
    const float* w_hh0 = (const float*)d_in[2];
    const float* b_ih0 = (const float*)d_in[3];
    const float* b_hh0 = (const float*)d_in[4];
    const float* w_ih1 = (const float*)d_in[5];
    const float* w_hh1 = (const float*)d_in[6];
    const float* b_ih1 = (const float*)d_in[7];
    const float* b_hh1 = (const float*)d_in[8];
    const float* fc_w  = (const float*)d_in[9];
    const float* fc_b  = (const float*)d_in[10];
    float* out = (float*)d_out;

    float* gi0 = (float*)d_ws;   // T*300 floats = 19.66 MB
    const size_t gi0_b = (size_t)T_STEPS * G_DIM * sizeof(float);

    // h1 history (ring1*100 fl) + a history (ringA*300 fl) + flags.
    // Full-history mode: producers never wait -> safe even if blocks
    // serialize (deps flow block0->1->2 in blockIdx order).
    int ring1, ringA, bp1, bpA;
    size_t need_full = gi0_b + (size_t)T_STEPS * H_DIM * 4 + (size_t)T_STEPS * G_DIM * 4 + 512;
    size_t need_mid  = gi0_b + (size_t)4096 * H_DIM * 4 + (size_t)2048 * G_DIM * 4 + 512;
    if (ws_size >= need_full)     { ring1 = T_STEPS; ringA = T_STEPS; bp1 = INT_MAX;   bpA = INT_MAX;   }
    else if (ws_size >= need_mid) { ring1 = 4096;    ringA = 2048;    bp1 = 4096 - 64; bpA = 2048 - 64; }
    else                          { ring1 = 1024;    ringA = 512;     bp1 = 1024 - 64; bpA = 512 - 64;  }

    float* h1g = (float*)((char*)d_ws + gi0_b);
    float* ag  = (float*)((char*)d_ws + gi0_b + (size_t)ring1 * H_DIM * sizeof(float));
    int* flags = (int*)((char*)ag + (size_t)ringA * G_DIM * sizeof(float));
    hipMemsetAsync(flags, 0, 512, stream);

    const int total = T_STEPS * G_DIM;
    gi0_kernel<<<(total + 255) / 256, 256, 0, stream>>>(x, w_ih0, b_ih0, gi0);
    gru3_kernel<<<3, 448, 0, stream>>>(gi0, w_hh0, b_hh0, w_ih1, b_ih1,
                                       w_hh1, b_hh1, fc_w, fc_b, out,
                                       h1g, ag, flags, ring1 - 1, ringA - 1, bp1, bpA);
}

// Round 6
// 18902.206 us; speedup vs baseline: 1.1813x; 1.1813x over previous
//
#include <hip/hip_runtime.h>
#include <math.h>

#define T_STEPS 16384
#define IN_DIM  14
#define H_DIM   100
#define G_DIM   300    // 3*H
#define WPAD    116    // LDS row stride in floats: dword stride 116 % 32 = 20,
                       // gcd(20,32)=4 -> 8 distinct b128 start banks covering all
                       // 32 banks uniformly across 64 lanes = pure-BW floor.
#define WQ      29     // WPAD/4 quads per row
#define SMEM_FLOATS (300*WPAD + 128 + 128 + 4*128)   // weights + bufA + bufB + ring
#define SMEM_BYTES  (SMEM_FLOATS * 4)                // 142272 B <= 160 KiB

typedef float f2 __attribute__((ext_vector_type(2)));
typedef float f4 __attribute__((ext_vector_type(4)));

// ---------------- Phase 0: gi0[t][j] = b_ih0[j] + sum_k x[t][k]*w_ih0[j][k] ----------------
__global__ void gi0_kernel(const float* __restrict__ x,
                           const float* __restrict__ w_ih0,
                           const float* __restrict__ b_ih0,
                           float* __restrict__ gi0) {
    int e = blockIdx.x * blockDim.x + threadIdx.x;
    if (e >= T_STEPS * G_DIM) return;
    int t = e / G_DIM;
    int j = e - t * G_DIM;
    const float* xr = x + t * IN_DIM;
    const float* wr = w_ih0 + j * IN_DIM;
    float acc = b_ih0[j];
    #pragma unroll
    for (int k = 0; k < IN_DIM; ++k) acc = fmaf(xr[k], wr[k], acc);
    gi0[e] = acc;
}

// ---------------- Phase 1: three persistent workgroups, WEIGHTS IN LDS ----------------
// ROUND 6. Root cause of R0-R5 (VGPR_Count 128/120/224/64/84/80 vs register
// plans of 200/200/400/100/100/100 floats/lane): the allocator ALWAYS demotes
// long-lived per-lane arrays to AGPRs (v_pk_fma can't read them -> ~1.5-2
// copy-VALU per weight float per iter), at every cap, with or without asm.
// Fix: weights live in LDS (no register pressure, reads pipeline, no tax).
//   B0: layer-0 recurrence over w_hh0[LDS]. Waves 0-4: r/z/n gate layout
//       (lane role=ln/20, q=wave*20+ln%20, row=role*100+q; bpermute combine
//       -- bit-exact chains from R3-R5). gi0 prefetched 1 step ahead into
//       registers (L3-resident, ~1 iter of latency cover). Wave 5: publishes
//       h1(t-1) to global + release flag every 4 steps.
//   B1: a(t)=b_ih1+w_ih1[LDS].h1(t). Waves 0-4: 60 rows/wave, store a direct
//       to global, per-wave release flag every 4 steps. Wave 5: depth-3
//       global->LDS ring prefetch of h1 (flag-gated).
//   B2: layer-1 recurrence over w_hh1[LDS]. r-lanes prefetch a(k+1) from
//       global 1 step ahead (gated by cached min of B1's 5 flags). + FC.
// Full-history h1/a buffers in workspace: producers NEVER wait -> deadlock-
// free even if blocks serialize (deps flow strictly B0->B1->B2).
// All accumulation chains / reduce order / gate math verbatim -> absmax 0.0.
__global__ __launch_bounds__(384, 2)
void gru_lds_kernel(const float* __restrict__ gi0,
                    const float* __restrict__ w_hh0, const float* __restrict__ b_hh0,
                    const float* __restrict__ w_ih1, const float* __restrict__ b_ih1,
                    const float* __restrict__ w_hh1, const float* __restrict__ b_hh1,
                    const float* __restrict__ fc_w,  const float* __restrict__ fc_b,
                    float* __restrict__ out,
                    float* __restrict__ h1g, float* __restrict__ ag, int* flags) {
    extern __shared__ float smem[];
    float* w_s  = smem;                    // 300*116 floats
    float* bufA = smem + 300 * WPAD;       // 128
    float* bufB = bufA + 128;              // 128
    float* ring = bufB + 128;              // 4*128 (B1 only)

    const int tid  = threadIdx.x;
    const int wave = tid >> 6;
    const int ln   = tid & 63;
    const int blk  = blockIdx.x;
    int* h1f = flags;                      // h1 steps published (B0 -> B1)
    int* af  = flags + 16;                 // af[w] at flags[16+16w]  (B1 -> B2)

    // ---- stage this block's weight matrix into LDS (one-time) ----
    const float* Wsrc = (blk == 0) ? w_hh0 : (blk == 1) ? w_ih1 : w_hh1;
    for (int i = tid; i < 300 * 25; i += 384) {
        int r = i / 25, k = i - r * 25;
        reinterpret_cast<f4*>(w_s)[r * WQ + k] =
            reinterpret_cast<const f4*>(Wsrc + (size_t)r * H_DIM)[k];
    }
    if (tid < 128) { bufA[tid] = 0.0f; bufB[tid] = 0.0f; }

    // gate-layout constants (waves 0-4 of B0/B2)
    const int ln20  = ln % 20;
    const int role  = ln / 20;
    const int roleC = (role > 2) ? 2 : role;
    const bool isR  = (role == 0);
    const int q     = wave * 20 + ln20;
    const int adZ   = (20 + ln20) << 2;
    const int adN   = (40 + ln20) << 2;

    if (blk == 0) {
        // =============== B0: layer-0 recurrence ===============
        const int row = roleC * 100 + q;
        const f4* wr4 = reinterpret_cast<const f4*>(w_s) + row * WQ;
        float bias = (wave < 5) ? b_hh0[row] : 0.0f;

        float c_r = 0.f, c_z = 0.f, c_n = 0.f, n_r = 0.f, n_z = 0.f, n_n = 0.f;
        if (wave < 5 && isR) {     // gi0(0)
            const float* p = gi0 + q;
            c_r = p[0]; c_z = p[H_DIM]; c_n = p[2 * H_DIM];
        }
        __syncthreads();

        for (int t = 0; t <= T_STEPS; ++t) {
            float* bc = (t & 1) ? bufB : bufA;
            float* bn = (t & 1) ? bufA : bufB;
            if (wave < 5) {
                if (isR && t + 1 < T_STEPS) {   // prefetch gi0(t+1)
                    const float* p = gi0 + (size_t)(t + 1) * G_DIM + q;
                    n_r = p[0]; n_z = p[H_DIM]; n_n = p[2 * H_DIM];
                }
                float hold = isR ? bc[q] : 0.f;
                const f4* hb4 = reinterpret_cast<const f4*>(bc);
                f2 accA, accB;
                accA.x = bias; accA.y = 0.f; accB.x = 0.f; accB.y = 0.f;
                #pragma unroll
                for (int k = 0; k < 25; ++k) {
                    f4 H = hb4[k]; f4 W = wr4[k];
                    accA += W.lo * H.lo; accB += W.hi * H.hi;
                }
                float d  = (accA.x + accB.x) + (accA.y + accB.y);
                float dz = __int_as_float(__builtin_amdgcn_ds_bpermute(adZ, __float_as_int(d)));
                float dn = __int_as_float(__builtin_amdgcn_ds_bpermute(adN, __float_as_int(d)));
                if (isR && t < T_STEPS) {
                    float r = 1.0f / (1.0f + expf(-(c_r + d)));
                    float z = 1.0f / (1.0f + expf(-(c_z + dz)));
                    float n = tanhf(c_n + r * dn);
                    bn[q] = (1.0f - z) * n + z * hold;
                }
                c_r = n_r; c_z = n_z; c_n = n_n;
            } else if (wave == 5) {
                if (t >= 1) {                   // publish h1(t-1) (in bc)
                    float* dst = h1g + (size_t)(t - 1) * H_DIM;
                    __hip_atomic_store(dst + ln, bc[ln], __ATOMIC_RELAXED, __HIP_MEMORY_SCOPE_AGENT);
                    if (ln < 36)
                        __hip_atomic_store(dst + 64 + ln, bc[64 + ln], __ATOMIC_RELAXED, __HIP_MEMORY_SCOPE_AGENT);
                    if ((t & 3) == 0 && ln == 0)   // release: drains this wave's stores only
                        __hip_atomic_store(h1f, t, __ATOMIC_RELEASE, __HIP_MEMORY_SCOPE_AGENT);
                }
            }
            __syncthreads();
        }
    } else if (blk == 1) {
        // =============== B1: a(t) = b_ih1 + w_ih1 . h1(t) ===============
        const int rl  = (ln < 60) ? ln : 59;
        const int row = wave * 60 + rl;
        const f4* wr4 = reinterpret_cast<const f4*>(w_s) + row * WQ;
        float bias = (wave < 5) ? b_ih1[row] : 0.0f;
        int* myaf = af + wave * 16;

        int h1c = 0;
        float rA0 = 0.f, rA1 = 0.f;
        if (wave == 5) {   // prologue: ring slots 0,1 + reg-stage h1(2)
            while (h1c < 3)
                h1c = __hip_atomic_load(h1f, __ATOMIC_ACQUIRE, __HIP_MEMORY_SCOPE_AGENT);
            for (int e = 0; e < 2; ++e) {
                float* src = h1g + (size_t)e * H_DIM;
                float* dst = ring + e * 128;
                dst[ln] = __hip_atomic_load(src + ln, __ATOMIC_RELAXED, __HIP_MEMORY_SCOPE_AGENT);
                if (ln < 36)
                    dst[64 + ln] = __hip_atomic_load(src + 64 + ln, __ATOMIC_RELAXED, __HIP_MEMORY_SCOPE_AGENT);
            }
            rA0 = __hip_atomic_load(h1g + 2 * H_DIM + ln, __ATOMIC_RELAXED, __HIP_MEMORY_SCOPE_AGENT);
            if (ln < 36)
                rA1 = __hip_atomic_load(h1g + 2 * H_DIM + 64 + ln, __ATOMIC_RELAXED, __HIP_MEMORY_SCOPE_AGENT);
        }
        __syncthreads();

        for (int u = 0; u < T_STEPS; ++u) {
            if (wave < 5) {
                const f4* hb4 = reinterpret_cast<const f4*>(ring + (u & 3) * 128);
                f2 accA, accB;
                accA.x = bias; accA.y = 0.f; accB.x = 0.f; accB.y = 0.f;
                #pragma unroll
                for (int k = 0; k < 25; ++k) {
                    f4 H = hb4[k]; f4 W = wr4[k];
                    accA += W.lo * H.lo; accB += W.hi * H.hi;
                }
                float d = (accA.x + accB.x) + (accA.y + accB.y);
                if (ln < 60)
                    __hip_atomic_store(ag + (size_t)u * G_DIM + row, d, __ATOMIC_RELAXED, __HIP_MEMORY_SCOPE_AGENT);
                if ((u & 3) == 3 && ln == 0)   // release drains this wave's a-stores
                    __hip_atomic_store(myaf, u + 1, __ATOMIC_RELEASE, __HIP_MEMORY_SCOPE_AGENT);
            } else if (wave == 5) {
                // async-split staging: write ring for (u+2) from regs, load (u+3)
                int ew = u + 2;
                if (ew < T_STEPS) {
                    float* dst = ring + (ew & 3) * 128;
                    dst[ln] = rA0;
                    if (ln < 36) dst[64 + ln] = rA1;
                }
                int el = u + 3;
                if (el < T_STEPS) {
                    while (h1c < el + 1)
                        h1c = __hip_atomic_load(h1f, __ATOMIC_ACQUIRE, __HIP_MEMORY_SCOPE_AGENT);
                    float* src = h1g + (size_t)el * H_DIM;
                    rA0 = __hip_atomic_load(src + ln, __ATOMIC_RELAXED, __HIP_MEMORY_SCOPE_AGENT);
                    if (ln < 36)
                        rA1 = __hip_atomic_load(src + 64 + ln, __ATOMIC_RELAXED, __HIP_MEMORY_SCOPE_AGENT);
                }
            }
            __syncthreads();
        }
    } else {
        // =============== B2: layer-1 recurrence + FC ===============
        const int row = roleC * 100 + q;
        const f4* wr4 = reinterpret_cast<const f4*>(w_s) + row * WQ;
        float bias = (wave < 5) ? b_hh1[row] : 0.0f;

        int am = 0;   // cached min over B1's 5 flags
        #define REFRESH(need) \
            while (am < (need)) { \
                int m0 = __hip_atomic_load(af +  0, __ATOMIC_ACQUIRE, __HIP_MEMORY_SCOPE_AGENT); \
                int m1 = __hip_atomic_load(af + 16, __ATOMIC_ACQUIRE, __HIP_MEMORY_SCOPE_AGENT); \
                int m2 = __hip_atomic_load(af + 32, __ATOMIC_ACQUIRE, __HIP_MEMORY_SCOPE_AGENT); \
                int m3 = __hip_atomic_load(af + 48, __ATOMIC_ACQUIRE, __HIP_MEMORY_SCOPE_AGENT); \
                int m4 = __hip_atomic_load(af + 64, __ATOMIC_ACQUIRE, __HIP_MEMORY_SCOPE_AGENT); \
                am = min(min(min(m0, m1), min(m2, m3)), m4); \
            }

        float c_r = 0.f, c_z = 0.f, c_n = 0.f, n_r = 0.f, n_z = 0.f, n_n = 0.f;
        if (wave < 5 && isR) {   // prologue: a(0)
            REFRESH(1);
            float* ap = ag + q;
            c_r = __hip_atomic_load(ap,             __ATOMIC_RELAXED, __HIP_MEMORY_SCOPE_AGENT);
            c_z = __hip_atomic_load(ap + H_DIM,     __ATOMIC_RELAXED, __HIP_MEMORY_SCOPE_AGENT);
            c_n = __hip_atomic_load(ap + 2 * H_DIM, __ATOMIC_RELAXED, __HIP_MEMORY_SCOPE_AGENT);
        }
        __syncthreads();

        for (int k2 = 0; k2 < T_STEPS; ++k2) {
            float* bc = (k2 & 1) ? bufB : bufA;
            float* bn = (k2 & 1) ? bufA : bufB;
            if (wave < 5) {
                if (isR && k2 + 1 < T_STEPS) {   // prefetch a(k2+1)
                    REFRESH(k2 + 2);
                    float* ap = ag + (size_t)(k2 + 1) * G_DIM + q;
                    n_r = __hip_atomic_load(ap,             __ATOMIC_RELAXED, __HIP_MEMORY_SCOPE_AGENT);
                    n_z = __hip_atomic_load(ap + H_DIM,     __ATOMIC_RELAXED, __HIP_MEMORY_SCOPE_AGENT);
                    n_n = __hip_atomic_load(ap + 2 * H_DIM, __ATOMIC_RELAXED, __HIP_MEMORY_SCOPE_AGENT);
                }
                float hold = isR ? bc[q] : 0.f;
                const f4* hb4 = reinterpret_cast<const f4*>(bc);
                f2 accA, accB;
                accA.x = bias; accA.y = 0.f; accB.x = 0.f; accB.y = 0.f;
                #pragma unroll
                for (int k = 0; k < 25; ++k) {
                    f4 H = hb4[k]; f4 W = wr4[k];
                    accA += W.lo * H.lo; accB += W.hi * H.hi;
                }
                float d  = (accA.x + accB.x) + (accA.y + accB.y);
                float dz = __int_as_float(__builtin_amdgcn_ds_bpermute(adZ, __float_as_int(d)));
                float dn = __int_as_float(__builtin_amdgcn_ds_bpermute(adN, __float_as_int(d)));
                if (isR) {
                    float r = 1.0f / (1.0f + expf(-(c_r + d)));
                    float z = 1.0f / (1.0f + expf(-(c_z + dz)));
                    float n = tanhf(c_n + r * dn);
                    bn[q] = (1.0f - z) * n + z * hold;
                }
                c_r = n_r; c_z = n_z; c_n = n_n;
            }
            __syncthreads();
        }
        #undef REFRESH

        // FC epilogue: h2(T-1) written at k2=T-1 (odd) -> bufA.
        if (tid < 64) {
            float s = 0.0f;
            for (int j = tid; j < H_DIM; j += 64) s = fmaf(fc_w[j], bufA[j], s);
            #pragma unroll
            for (int off = 32; off > 0; off >>= 1) s += __shfl_down(s, off);
            if (tid == 0) out[0] = s + fc_b[0];
        }
    }
}

extern "C" void kernel_launch(void* const* d_in, const int* in_sizes, int n_in,
                              void* d_out, int out_size, void* d_ws, size_t ws_size,
                              hipStream_t stream) {
    const float* x     = (const float*)d_in[0];
    const float* w_ih0 = (const float*)d_in[1];
    const float* w_hh0 = (const float*)d_in[2];
    const float* b_ih0 = (const float*)d_in[3];
    const float* b_hh0 = (const float*)d_in[4];
    const float* w_ih1 = (const float*)d_in[5];
    const float* w_hh1 = (const float*)d_in[6];
    const float* b_ih1 = (const float*)d_in[7];
    const float* b_hh1 = (const float*)d_in[8];
    const float* fc_w  = (const float*)d_in[9];
    const float* fc_b  = (const float*)d_in[10];
    float* out = (float*)d_out;

    float* gi0 = (float*)d_ws;                                     // 19.66 MB
    const size_t gi0_b = (size_t)T_STEPS * G_DIM * sizeof(float);
    float* h1g = (float*)((char*)d_ws + gi0_b);                    // 6.55 MB (full history)
    float* ag  = (float*)((char*)h1g + (size_t)T_STEPS * H_DIM * sizeof(float)); // 19.66 MB
    int* flags = (int*)((char*)ag + (size_t)T_STEPS * G_DIM * sizeof(float));
    hipMemsetAsync(flags, 0, 512, stream);   // reset h1f/af each launch

    // one-time-safe: allow 142 KB dynamic LDS (160 KB/CU on gfx950)
    static bool attr_set = false;
    if (!attr_set) {
        hipFuncSetAttribute(reinterpret_cast<const void*>(&gru_lds_kernel),
                            hipFuncAttributeMaxDynamicSharedMemorySize, SMEM_BYTES);
        attr_set = true;
    }

    const int total = T_STEPS * G_DIM;
    gi0_kernel<<<(total + 255) / 256, 256, 0, stream>>>(x, w_ih0, b_ih0, gi0);
    gru_lds_kernel<<<3, 384, SMEM_BYTES, stream>>>(gi0, w_hh0, b_hh0, w_ih1, b_ih1,
                                                   w_hh1, b_hh1, fc_w, fc_b, out,
                                                   h1g, ag, flags);
}